// Round 2
// baseline (3464.358 us; speedup 1.0000x reference)
//
#include <hip/hip_runtime.h>
#include <math.h>

#define VOCAB 267735
#define NTOK  512

// ---------------- block reductions ----------------
__device__ __forceinline__ float block_reduce_max(float v, float* sm) {
    #pragma unroll
    for (int off = 32; off > 0; off >>= 1)
        v = fmaxf(v, __shfl_down(v, off, 64));
    int wid  = threadIdx.x >> 6;
    int lane = threadIdx.x & 63;
    int nw   = (int)(blockDim.x >> 6);
    if (lane == 0) sm[wid] = v;
    __syncthreads();
    if (threadIdx.x == 0) {
        float m = sm[0];
        for (int i = 1; i < nw; ++i) m = fmaxf(m, sm[i]);
        sm[0] = m;
    }
    __syncthreads();
    float r = sm[0];
    __syncthreads();
    return r;
}

__device__ __forceinline__ float block_reduce_sum(float v, float* sm) {
    #pragma unroll
    for (int off = 32; off > 0; off >>= 1)
        v += __shfl_down(v, off, 64);
    int wid  = threadIdx.x >> 6;
    int lane = threadIdx.x & 63;
    int nw   = (int)(blockDim.x >> 6);
    if (lane == 0) sm[wid] = v;
    __syncthreads();
    if (threadIdx.x == 0) {
        float s = sm[0];
        for (int i = 1; i < nw; ++i) s += sm[i];
        sm[0] = s;
    }
    __syncthreads();
    float r = sm[0];
    __syncthreads();
    return r;
}

// ---------------- GEMM: C = A @ B^T + bias ----------------
// A: [M,K] row-major; B: [N,K] row-major; C row-major with leading dim ldc.
#define BM 64
#define BN 64
#define BKK 16

__global__ __launch_bounds__(256) void gemm_abT(
    const float* __restrict__ A, const float* __restrict__ B,
    const float* __restrict__ bias, float* __restrict__ C,
    int M, int N, int K, int ldc)
{
    __shared__ float As[BM][BKK + 1];   // [m][k]
    __shared__ float Bs[BN][BKK + 1];   // [n][k]
    const int tid = threadIdx.x;
    const int tx = tid & 15;    // n group
    const int ty = tid >> 4;    // m group
    const int mBase = blockIdx.y * BM;
    const int nBase = blockIdx.x * BN;

    float acc[4][4] = {};
    for (int k0 = 0; k0 < K; k0 += BKK) {
        #pragma unroll
        for (int e = 0; e < 4; ++e) {
            int idx = tid + e * 256;
            int m = idx >> 4, k = idx & 15;
            int gm = mBase + m;
            As[m][k] = (gm < M) ? A[(size_t)gm * K + k0 + k] : 0.f;
        }
        #pragma unroll
        for (int e = 0; e < 4; ++e) {
            int idx = tid + e * 256;
            int n = idx >> 4, k = idx & 15;
            int gn = nBase + n;
            Bs[n][k] = (gn < N) ? B[(size_t)gn * K + k0 + k] : 0.f;
        }
        __syncthreads();
        #pragma unroll
        for (int k = 0; k < BKK; ++k) {
            float a[4], b[4];
            #pragma unroll
            for (int i = 0; i < 4; ++i) a[i] = As[ty * 4 + i][k];
            #pragma unroll
            for (int j = 0; j < 4; ++j) b[j] = Bs[tx * 4 + j][k];
            #pragma unroll
            for (int i = 0; i < 4; ++i)
                #pragma unroll
                for (int j = 0; j < 4; ++j)
                    acc[i][j] = fmaf(a[i], b[j], acc[i][j]);
        }
        __syncthreads();
    }
    #pragma unroll
    for (int i = 0; i < 4; ++i) {
        int gm = mBase + ty * 4 + i;
        if (gm >= M) continue;
        #pragma unroll
        for (int j = 0; j < 4; ++j) {
            int gn = nBase + tx * 4 + j;
            if (gn < N)
                C[(size_t)gm * ldc + gn] = acc[i][j] + (bias ? bias[gn] : 0.f);
        }
    }
}

// ---------------- head log-softmax (20000 shortlist + 3 cluster logits) ----------------
__global__ __launch_bounds__(256) void head_logsoftmax(
    float* __restrict__ out, const float* __restrict__ hc_logits,
    float* __restrict__ hc_logprob)
{
    const int t = blockIdx.x;
    float* row = out + (size_t)t * VOCAB;
    const float* hc = hc_logits + t * 3;
    const int N = 20003;
    __shared__ float sm[8];

    float mx = -INFINITY;
    for (int i = threadIdx.x; i < N; i += blockDim.x) {
        float v = (i < 20000) ? row[i] : hc[i - 20000];
        mx = fmaxf(mx, v);
    }
    mx = block_reduce_max(mx, sm);

    float s = 0.f;
    for (int i = threadIdx.x; i < N; i += blockDim.x) {
        float v = (i < 20000) ? row[i] : hc[i - 20000];
        s += __expf(v - mx);
    }
    s = block_reduce_sum(s, sm);
    const float lse = mx + __logf(s);

    for (int i = threadIdx.x; i < N; i += blockDim.x) {
        if (i < 20000) row[i] = row[i] - lse;
        else           hc_logprob[t * 3 + (i - 20000)] = hc[i - 20000] - lse;
    }
}

// ---------------- tail log-softmax (+ head cluster logprob offset) ----------------
__global__ __launch_bounds__(256) void tail_logsoftmax(
    float* __restrict__ out, const float* __restrict__ hc_logprob,
    int seg_off, int N, int ci)
{
    const int t = blockIdx.x;
    float* row = out + (size_t)t * VOCAB + seg_off;
    __shared__ float sm[8];

    float mx = -INFINITY;
    for (int i = threadIdx.x; i < N; i += blockDim.x) mx = fmaxf(mx, row[i]);
    mx = block_reduce_max(mx, sm);

    float s = 0.f;
    for (int i = threadIdx.x; i < N; i += blockDim.x) s += __expf(row[i] - mx);
    s = block_reduce_sum(s, sm);

    const float add = hc_logprob[t * 3 + ci - 1] - (mx + __logf(s));
    for (int i = threadIdx.x; i < N; i += blockDim.x) row[i] += add;
}

// ---------------- loss: mean over 512 tokens of -out[t, target[t]] ----------------
__global__ __launch_bounds__(512) void loss_kernel(
    const float* __restrict__ out, const int* __restrict__ target,
    float* __restrict__ loss)
{
    __shared__ float sm[8];
    const int t = threadIdx.x;   // 512 threads == NTOK
    float v = -out[(size_t)t * VOCAB + target[t]];
    float s = block_reduce_sum(v, sm);
    if (threadIdx.x == 0) *loss = s / (float)NTOK;
}

// ---------------- launch ----------------
extern "C" void kernel_launch(void* const* d_in, const int* in_sizes, int n_in,
                              void* d_out, int out_size, void* d_ws, size_t ws_size,
                              hipStream_t stream)
{
    const float* hidden = (const float*)d_in[0];
    const int*   target = (const int*)d_in[1];
    const float* cw     = (const float*)d_in[2];
    const float* cb     = (const float*)d_in[3];
    const float* proj[4] = {(const float*)d_in[4], (const float*)d_in[7],
                            (const float*)d_in[10], (const float*)d_in[13]};
    const float* W[4]    = {(const float*)d_in[5], (const float*)d_in[8],
                            (const float*)d_in[11], (const float*)d_in[14]};
    const float* b[4]    = {(const float*)d_in[6], (const float*)d_in[9],
                            (const float*)d_in[12], (const float*)d_in[15]};
    float* out = (float*)d_out;
    float* ws  = (float*)d_ws;

    float* Y0   = ws;                    // [512][1024]
    float* Y1   = Y0 + NTOK * 1024;      // [512][256]
    float* Y2   = Y1 + NTOK * 256;       // [512][64]
    float* Y3   = Y2 + NTOK * 64;        // [512][16]
    float* hcl  = Y3 + NTOK * 16;        // [512][3] cluster logits
    float* hclp = hcl + NTOK * 3;        // [512][3] cluster logprobs

    dim3 blk(256);
    // projections: Y_i = hidden @ proj_i^T
    gemm_abT<<<dim3((1024 + BN - 1) / BN, NTOK / BM), blk, 0, stream>>>(hidden, proj[0], nullptr, Y0, NTOK, 1024, 1024, 1024);
    gemm_abT<<<dim3((256  + BN - 1) / BN, NTOK / BM), blk, 0, stream>>>(hidden, proj[1], nullptr, Y1, NTOK, 256, 1024, 256);
    gemm_abT<<<dim3(1, NTOK / BM), blk, 0, stream>>>(hidden, proj[2], nullptr, Y2, NTOK, 64, 1024, 64);
    gemm_abT<<<dim3(1, NTOK / BM), blk, 0, stream>>>(hidden, proj[3], nullptr, Y3, NTOK, 16, 1024, 16);

    // head cluster logits: computed from the PROJECTED hidden Y0 (head_W = [W_0; cluster_weight] applied to y0)
    gemm_abT<<<dim3(1, NTOK / BM), blk, 0, stream>>>(Y0, cw, cb, hcl, NTOK, 3, 1024, 3);

    // raw logits straight into out slices
    gemm_abT<<<dim3((20000 + BN - 1) / BN, NTOK / BM), blk, 0, stream>>>(Y0, W[0], b[0], out,          NTOK, 20000,  1024, VOCAB);
    gemm_abT<<<dim3((20000 + BN - 1) / BN, NTOK / BM), blk, 0, stream>>>(Y1, W[1], b[1], out + 20000,  NTOK, 20000,  256,  VOCAB);
    gemm_abT<<<dim3((160000 + BN - 1) / BN, NTOK / BM), blk, 0, stream>>>(Y2, W[2], b[2], out + 40000,  NTOK, 160000, 64,   VOCAB);
    gemm_abT<<<dim3((67735 + BN - 1) / BN, NTOK / BM), blk, 0, stream>>>(Y3, W[3], b[3], out + 200000, NTOK, 67735,  16,   VOCAB);

    // log-softmaxes
    head_logsoftmax<<<NTOK, 256, 0, stream>>>(out, hcl, hclp);
    tail_logsoftmax<<<NTOK, 256, 0, stream>>>(out, hclp, 20000,  20000,  1);
    tail_logsoftmax<<<NTOK, 256, 0, stream>>>(out, hclp, 40000,  160000, 2);
    tail_logsoftmax<<<NTOK, 256, 0, stream>>>(out, hclp, 200000, 67735,  3);

    // loss
    loss_kernel<<<1, NTOK, 0, stream>>>(out, target, out + (size_t)NTOK * VOCAB);
}

// Round 3
// 2584.885 us; speedup vs baseline: 1.3402x; 1.3402x over previous
//
#include <hip/hip_runtime.h>
#include <math.h>

#define VOCAB 267735
#define NTOK  512

// ---------------- GEMM: C = A @ B^T + bias, optional per-row sum(exp(C)) ----------------
// A: [M,K] row-major; B: [N,K] row-major; C row-major leading dim ldc.
// rowsum != nullptr: atomicAdd per-row partial sum of exp(C) into rowsum[row].
#define BM 64
#define BN 64
#define BKK 16

__global__ __launch_bounds__(256) void gemm_abT_stats(
    const float* __restrict__ A, const float* __restrict__ B,
    const float* __restrict__ bias, float* __restrict__ C,
    float* __restrict__ rowsum,
    int M, int N, int K, int ldc)
{
    __shared__ float As[BKK][BM + 4];   // [k][m], +4 keeps rows 16B-aligned
    __shared__ float Bs[BKK][BN + 4];   // [k][n]
    const int tid = threadIdx.x;
    const int tx = tid & 15;    // n group (lanes 0..15 within 16-lane group)
    const int ty = tid >> 4;    // m group
    const int mBase = blockIdx.y * BM;
    const int nBase = blockIdx.x * BN;

    float acc[4][4] = {};
    for (int k0 = 0; k0 < K; k0 += BKK) {
        #pragma unroll
        for (int e = 0; e < 4; ++e) {
            int idx = tid + e * 256;
            int m = idx >> 4, k = idx & 15;
            int gm = mBase + m;
            As[k][m] = (gm < M) ? A[(size_t)gm * K + k0 + k] : 0.f;
        }
        #pragma unroll
        for (int e = 0; e < 4; ++e) {
            int idx = tid + e * 256;
            int n = idx >> 4, k = idx & 15;
            int gn = nBase + n;
            Bs[k][n] = (gn < N) ? B[(size_t)gn * K + k0 + k] : 0.f;
        }
        __syncthreads();
        #pragma unroll
        for (int k = 0; k < BKK; ++k) {
            float4 a4 = *(const float4*)&As[k][ty * 4];
            float4 b4 = *(const float4*)&Bs[k][tx * 4];
            float a[4] = {a4.x, a4.y, a4.z, a4.w};
            float b[4] = {b4.x, b4.y, b4.z, b4.w};
            #pragma unroll
            for (int i = 0; i < 4; ++i)
                #pragma unroll
                for (int j = 0; j < 4; ++j)
                    acc[i][j] = fmaf(a[i], b[j], acc[i][j]);
        }
        __syncthreads();
    }

    float part[4] = {0.f, 0.f, 0.f, 0.f};
    #pragma unroll
    for (int i = 0; i < 4; ++i) {
        int gm = mBase + ty * 4 + i;
        if (gm >= M) continue;
        #pragma unroll
        for (int j = 0; j < 4; ++j) {
            int gn = nBase + tx * 4 + j;
            if (gn < N) {
                float v = acc[i][j] + (bias ? bias[gn] : 0.f);
                C[(size_t)gm * ldc + gn] = v;
                part[i] += __expf(v);
            }
        }
    }

    if (rowsum) {
        #pragma unroll
        for (int i = 0; i < 4; ++i) {
            float p = part[i];
            #pragma unroll
            for (int m = 8; m >= 1; m >>= 1)
                p += __shfl_xor(p, m, 16);
            if (tx == 0) {
                int gm = mBase + ty * 4 + i;
                if (gm < M) atomicAdd(&rowsum[gm], p);
            }
        }
    }
}

// ---------------- finish: per-token segment offsets ----------------
// rs: [4][NTOK] sum(exp(logits)) per segment; hcl: [NTOK][3] cluster logits.
// adds[t][0] = -lse_head ; adds[t][i] = (hcl[i-1]-lse_head) - lse_i
__global__ __launch_bounds__(256) void finish_kernel(
    const float* __restrict__ rs, const float* __restrict__ hcl,
    float* __restrict__ adds)
{
    int t = blockIdx.x * blockDim.x + threadIdx.x;
    if (t >= NTOK) return;
    float h0 = hcl[t * 3 + 0], h1 = hcl[t * 3 + 1], h2 = hcl[t * 3 + 2];
    float s_head = rs[0 * NTOK + t] + __expf(h0) + __expf(h1) + __expf(h2);
    float lse_head = __logf(s_head);
    adds[t * 4 + 0] = -lse_head;
    adds[t * 4 + 1] = (h0 - lse_head) - __logf(rs[1 * NTOK + t]);
    adds[t * 4 + 2] = (h1 - lse_head) - __logf(rs[2 * NTOK + t]);
    adds[t * 4 + 3] = (h2 - lse_head) - __logf(rs[3 * NTOK + t]);
}

// ---------------- apply: out[t][v] += adds[t][seg(v)] (float4 grid-stride) ----------------
__global__ __launch_bounds__(256) void apply_kernel(
    float* __restrict__ out, const float* __restrict__ adds)
{
    const size_t numel4 = (size_t)NTOK * VOCAB / 4;   // divisible by 4
    size_t stride = (size_t)gridDim.x * blockDim.x;
    for (size_t i4 = (size_t)blockIdx.x * blockDim.x + threadIdx.x;
         i4 < numel4; i4 += stride) {
        size_t base = i4 * 4;
        size_t t0 = base / VOCAB;
        int v0 = (int)(base - t0 * VOCAB);
        float4 x = *(float4*)&out[base];
        float vals[4] = {x.x, x.y, x.z, x.w};
        #pragma unroll
        for (int j = 0; j < 4; ++j) {
            int vj = v0 + j;
            size_t tj = t0;
            if (vj >= VOCAB) { vj -= VOCAB; tj++; }
            int seg = (vj < 20000) ? 0 : (vj < 40000) ? 1 : (vj < 200000) ? 2 : 3;
            vals[j] += adds[tj * 4 + seg];
        }
        x.x = vals[0]; x.y = vals[1]; x.z = vals[2]; x.w = vals[3];
        *(float4*)&out[base] = x;
    }
}

// ---------------- loss ----------------
__global__ __launch_bounds__(512) void loss_kernel(
    const float* __restrict__ out, const int* __restrict__ target,
    float* __restrict__ loss)
{
    __shared__ float sm[8];
    const int t = threadIdx.x;   // 512 threads == NTOK
    float v = -out[(size_t)t * VOCAB + target[t]];
    #pragma unroll
    for (int off = 32; off > 0; off >>= 1)
        v += __shfl_down(v, off, 64);
    int wid = threadIdx.x >> 6, lane = threadIdx.x & 63;
    if (lane == 0) sm[wid] = v;
    __syncthreads();
    if (threadIdx.x == 0) {
        float s = 0.f;
        for (int i = 0; i < 8; ++i) s += sm[i];
        *loss = s / (float)NTOK;
    }
}

// ---------------- launch ----------------
extern "C" void kernel_launch(void* const* d_in, const int* in_sizes, int n_in,
                              void* d_out, int out_size, void* d_ws, size_t ws_size,
                              hipStream_t stream)
{
    const float* hidden = (const float*)d_in[0];
    const int*   target = (const int*)d_in[1];
    const float* cw     = (const float*)d_in[2];
    const float* cb     = (const float*)d_in[3];
    const float* proj[4] = {(const float*)d_in[4], (const float*)d_in[7],
                            (const float*)d_in[10], (const float*)d_in[13]};
    const float* W[4]    = {(const float*)d_in[5], (const float*)d_in[8],
                            (const float*)d_in[11], (const float*)d_in[14]};
    const float* b[4]    = {(const float*)d_in[6], (const float*)d_in[9],
                            (const float*)d_in[12], (const float*)d_in[15]};
    float* out = (float*)d_out;
    float* ws  = (float*)d_ws;

    float* Y0   = ws;                    // [512][1024]
    float* Y1   = Y0 + NTOK * 1024;      // [512][256]
    float* Y2   = Y1 + NTOK * 256;       // [512][64]
    float* Y3   = Y2 + NTOK * 64;        // [512][16]
    float* hcl  = Y3 + NTOK * 16;        // [512][3]  cluster logits
    float* rs   = hcl + NTOK * 3;        // [4][512]  per-segment sum(exp)
    float* adds = rs + 4 * NTOK;         // [512][4]  per-token segment offsets

    hipMemsetAsync(rs, 0, 4 * NTOK * sizeof(float), stream);

    dim3 blk(256);
    // projections: Y_i = hidden @ proj_i^T (no stats)
    gemm_abT_stats<<<dim3(1024 / BN, NTOK / BM), blk, 0, stream>>>(hidden, proj[0], nullptr, Y0, nullptr, NTOK, 1024, 1024, 1024);
    gemm_abT_stats<<<dim3(256  / BN, NTOK / BM), blk, 0, stream>>>(hidden, proj[1], nullptr, Y1, nullptr, NTOK, 256, 1024, 256);
    gemm_abT_stats<<<dim3(1, NTOK / BM), blk, 0, stream>>>(hidden, proj[2], nullptr, Y2, nullptr, NTOK, 64, 1024, 64);
    gemm_abT_stats<<<dim3(1, NTOK / BM), blk, 0, stream>>>(hidden, proj[3], nullptr, Y3, nullptr, NTOK, 16, 1024, 16);

    // head cluster logits from PROJECTED hidden Y0 (head_W = [W_0; cluster_weight] @ y0)
    gemm_abT_stats<<<dim3(1, NTOK / BM), blk, 0, stream>>>(Y0, cw, cb, hcl, nullptr, NTOK, 3, 1024, 3);

    // logits into out slices, fused sum(exp) per row
    gemm_abT_stats<<<dim3((20000 + BN - 1) / BN, NTOK / BM), blk, 0, stream>>>(Y0, W[0], b[0], out,          rs + 0 * NTOK, NTOK, 20000,  1024, VOCAB);
    gemm_abT_stats<<<dim3((20000 + BN - 1) / BN, NTOK / BM), blk, 0, stream>>>(Y1, W[1], b[1], out + 20000,  rs + 1 * NTOK, NTOK, 20000,  256,  VOCAB);
    gemm_abT_stats<<<dim3((160000 + BN - 1) / BN, NTOK / BM), blk, 0, stream>>>(Y2, W[2], b[2], out + 40000,  rs + 2 * NTOK, NTOK, 160000, 64,   VOCAB);
    gemm_abT_stats<<<dim3((67735 + BN - 1) / BN, NTOK / BM), blk, 0, stream>>>(Y3, W[3], b[3], out + 200000, rs + 3 * NTOK, NTOK, 67735,  16,   VOCAB);

    finish_kernel<<<2, 256, 0, stream>>>(rs, hcl, adds);
    apply_kernel<<<4096, 256, 0, stream>>>(out, adds);
    loss_kernel<<<1, NTOK, 0, stream>>>(out, target, out + (size_t)NTOK * VOCAB);
}

// Round 4
// 1287.711 us; speedup vs baseline: 2.6903x; 2.0073x over previous
//
#include <hip/hip_runtime.h>
#include <math.h>

#define VOCAB 267735
#define NTOK  512
#define BM 128
#define BN 128
#define BK 32
#define CDIV(a,b) (((a)+(b)-1)/(b))

typedef __bf16 bf16x8 __attribute__((ext_vector_type(8)));
typedef float f32x4 __attribute__((ext_vector_type(4)));
typedef const __attribute__((address_space(1))) void* gas_ptr;
typedef __attribute__((address_space(3))) void* las_ptr;

__device__ __forceinline__ unsigned short f2bf(float x) {
    unsigned int u = __float_as_uint(x);
    u = (u + 0x7FFFu + ((u >> 16) & 1u)) >> 16;
    return (unsigned short)u;
}
__device__ __forceinline__ float bf2f(unsigned short h) {
    return __uint_as_float(((unsigned int)h) << 16);
}
__device__ __forceinline__ void gload_lds16(const void* g, void* l) {
    __builtin_amdgcn_global_load_lds((gas_ptr)g, (las_ptr)l, 16, 0, 0);
}

// ---------------- fp32 -> bf16 conversion (float4 -> ushort4) ----------------
__global__ __launch_bounds__(256) void conv_bf16(
    const float* __restrict__ src, unsigned short* __restrict__ dst, int n4)
{
    int i = blockIdx.x * blockDim.x + threadIdx.x;
    if (i < n4) {
        float4 f = ((const float4*)src)[i];
        ushort4 o;
        o.x = f2bf(f.x); o.y = f2bf(f.y); o.z = f2bf(f.z); o.w = f2bf(f.w);
        ((ushort4*)dst)[i] = o;
    }
}

// ---------------- MFMA GEMM: C = A(bf16) @ B(f32->bf16)^T ----------------
// A: [M][lda] bf16 (staged via global_load_lds). B: [N][KB] fp32 (reg-staged,
// zero-padded for k>=KB). K = loop extent (multiple of 32).
// MODE 0: store bf16 to Yo (ld ldo; zero-fill N<=gn<ldo)
// MODE 1: rowsum[gm] += sum_n exp(acc + bias[gn])          (no C store)
// MODE 2: C[gm*ldc+gn] = acc + bias[gn] + adds[gm*4+seg]
template<int MODE>
__global__ __launch_bounds__(256) void mfma_gemm(
    const unsigned short* __restrict__ Ab, const float* __restrict__ Bf,
    const float* __restrict__ bias,
    float* __restrict__ C, int ldc,
    unsigned short* __restrict__ Yo, int ldo,
    float* __restrict__ rowsum,
    const float* __restrict__ adds, int seg,
    int N, int K, int lda, int KB)
{
    __shared__ unsigned short As[BM * BK];
    __shared__ unsigned short Bs[BN * BK];
    const int tid  = threadIdx.x;
    const int lane = tid & 63;
    const int w    = tid >> 6;
    const int wm   = w >> 1, wn = w & 1;
    const int mBase = blockIdx.y * BM;
    const int nBase = blockIdx.x * BN;
    const int col = lane & 15, rg = lane >> 4;

    f32x4 acc[4][4] = {};

    for (int k0 = 0; k0 < K; k0 += BK) {
        // A: 2 x 16B global_load_lds per thread, linear LDS = [m][k] row-major
        #pragma unroll
        for (int i = 0; i < 2; ++i) {
            int c = tid + i * 256;              // 0..511
            int m = c >> 2, k8 = (c & 3) * 8;
            const unsigned short* g = Ab + (size_t)(mBase + m) * lda + k0 + k8;
            gload_lds16(g, &As[(size_t)c * 8]);
        }
        // B: reg-stage fp32 -> bf16 (4 chunks of 4 floats per thread)
        #pragma unroll
        for (int i = 0; i < 4; ++i) {
            int c = tid + i * 256;              // 0..1023
            int n = c >> 3, k = (c & 7) * 4;
            int gn = nBase + n; if (gn >= N) gn = N - 1;
            int kg = k0 + k;
            float4 f = make_float4(0.f, 0.f, 0.f, 0.f);
            if (kg < KB) f = *(const float4*)(Bf + (size_t)gn * KB + kg);
            ushort4 o;
            o.x = f2bf(f.x); o.y = f2bf(f.y); o.z = f2bf(f.z); o.w = f2bf(f.w);
            *(ushort4*)&Bs[n * BK + k] = o;
        }
        __syncthreads();
        bf16x8 af[4], bfr[4];
        #pragma unroll
        for (int mi = 0; mi < 4; ++mi) {
            int row = wm * 64 + mi * 16 + col;
            af[mi] = *(const bf16x8*)&As[row * BK + rg * 8];
        }
        #pragma unroll
        for (int ni = 0; ni < 4; ++ni) {
            int row = wn * 64 + ni * 16 + col;
            bfr[ni] = *(const bf16x8*)&Bs[row * BK + rg * 8];
        }
        #pragma unroll
        for (int mi = 0; mi < 4; ++mi)
            #pragma unroll
            for (int ni = 0; ni < 4; ++ni)
                acc[mi][ni] = __builtin_amdgcn_mfma_f32_16x16x32_bf16(
                    af[mi], bfr[ni], acc[mi][ni], 0, 0, 0);
        __syncthreads();
    }

    if (MODE == 1) {
        #pragma unroll
        for (int mi = 0; mi < 4; ++mi) {
            float part[4] = {0.f, 0.f, 0.f, 0.f};
            #pragma unroll
            for (int ni = 0; ni < 4; ++ni) {
                int gn = nBase + wn * 64 + ni * 16 + col;
                if (gn < N) {
                    float bv = bias[gn];
                    #pragma unroll
                    for (int r = 0; r < 4; ++r)
                        part[r] += __expf(acc[mi][ni][r] + bv);
                }
            }
            int gm = mBase + wm * 64 + mi * 16 + rg * 4;
            #pragma unroll
            for (int r = 0; r < 4; ++r) {
                float v = part[r];
                #pragma unroll
                for (int s = 8; s >= 1; s >>= 1) v += __shfl_xor(v, s, 16);
                if (col == 0) atomicAdd(&rowsum[gm + r], v);
            }
        }
    } else if (MODE == 2) {
        #pragma unroll
        for (int mi = 0; mi < 4; ++mi) {
            int gm = mBase + wm * 64 + mi * 16 + rg * 4;
            float av[4];
            #pragma unroll
            for (int r = 0; r < 4; ++r) av[r] = adds[(gm + r) * 4 + seg];
            #pragma unroll
            for (int ni = 0; ni < 4; ++ni) {
                int gn = nBase + wn * 64 + ni * 16 + col;
                if (gn < N) {
                    float bv = bias[gn];
                    #pragma unroll
                    for (int r = 0; r < 4; ++r)
                        C[(size_t)(gm + r) * ldc + gn] = acc[mi][ni][r] + bv + av[r];
                }
            }
        }
    } else {
        #pragma unroll
        for (int mi = 0; mi < 4; ++mi) {
            int gm = mBase + wm * 64 + mi * 16 + rg * 4;
            #pragma unroll
            for (int ni = 0; ni < 4; ++ni) {
                int gn = nBase + wn * 64 + ni * 16 + col;
                if (gn < ldo) {
                    #pragma unroll
                    for (int r = 0; r < 4; ++r) {
                        float v = (gn < N) ? acc[mi][ni][r] : 0.f;
                        Yo[(size_t)(gm + r) * ldo + gn] = f2bf(v);
                    }
                }
            }
        }
    }
}

// ---------------- cluster logits: hcl[t][j] = dot(Y0b[t], cw[j]) + cb[j] ----------------
__global__ __launch_bounds__(256) void hcl_kernel(
    const unsigned short* __restrict__ Y0b, const float* __restrict__ cw,
    const float* __restrict__ cb, float* __restrict__ hcl)
{
    int t = blockIdx.x;
    int w = threadIdx.x >> 6, l = threadIdx.x & 63;
    if (w >= 3) return;
    const unsigned short* yrow = Y0b + (size_t)t * 1024;
    float s = 0.f;
    #pragma unroll
    for (int e = 0; e < 16; ++e) {
        int k = l * 16 + e;
        s += bf2f(yrow[k]) * cw[w * 1024 + k];
    }
    #pragma unroll
    for (int off = 32; off > 0; off >>= 1) s += __shfl_down(s, off, 64);
    if (l == 0) hcl[t * 3 + w] = s + cb[w];
}

// ---------------- finish: per-token segment offsets ----------------
__global__ __launch_bounds__(256) void finish_kernel(
    const float* __restrict__ rs, const float* __restrict__ hcl,
    float* __restrict__ adds)
{
    int t = blockIdx.x * blockDim.x + threadIdx.x;
    if (t >= NTOK) return;
    float h0 = hcl[t * 3 + 0], h1 = hcl[t * 3 + 1], h2 = hcl[t * 3 + 2];
    float s_head = rs[0 * NTOK + t] + __expf(h0) + __expf(h1) + __expf(h2);
    float lse_head = __logf(s_head);
    adds[t * 4 + 0] = -lse_head;
    adds[t * 4 + 1] = (h0 - lse_head) - __logf(rs[1 * NTOK + t]);
    adds[t * 4 + 2] = (h1 - lse_head) - __logf(rs[2 * NTOK + t]);
    adds[t * 4 + 3] = (h2 - lse_head) - __logf(rs[3 * NTOK + t]);
}

// ---------------- loss ----------------
__global__ __launch_bounds__(512) void loss_kernel(
    const float* __restrict__ out, const int* __restrict__ target,
    float* __restrict__ loss)
{
    __shared__ float sm[8];
    const int t = threadIdx.x;
    float v = -out[(size_t)t * VOCAB + target[t]];
    #pragma unroll
    for (int off = 32; off > 0; off >>= 1) v += __shfl_down(v, off, 64);
    int wid = threadIdx.x >> 6, lane = threadIdx.x & 63;
    if (lane == 0) sm[wid] = v;
    __syncthreads();
    if (threadIdx.x == 0) {
        float s = 0.f;
        for (int i = 0; i < 8; ++i) s += sm[i];
        *loss = s / (float)NTOK;
    }
}

// ---------------- launch ----------------
extern "C" void kernel_launch(void* const* d_in, const int* in_sizes, int n_in,
                              void* d_out, int out_size, void* d_ws, size_t ws_size,
                              hipStream_t stream)
{
    const float* hidden = (const float*)d_in[0];
    const int*   target = (const int*)d_in[1];
    const float* cw     = (const float*)d_in[2];
    const float* cb     = (const float*)d_in[3];
    const float* proj[4] = {(const float*)d_in[4], (const float*)d_in[7],
                            (const float*)d_in[10], (const float*)d_in[13]};
    const float* W[4]    = {(const float*)d_in[5], (const float*)d_in[8],
                            (const float*)d_in[11], (const float*)d_in[14]};
    const float* b[4]    = {(const float*)d_in[6], (const float*)d_in[9],
                            (const float*)d_in[12], (const float*)d_in[15]};
    float* out = (float*)d_out;
    char*  w8  = (char*)d_ws;

    unsigned short* Hb  = (unsigned short*)(w8 + 0);         // [512][1024]
    unsigned short* Y0b = (unsigned short*)(w8 + 1048576);   // [512][1024]
    unsigned short* Y1b = (unsigned short*)(w8 + 2097152);   // [512][256]
    unsigned short* Y2b = (unsigned short*)(w8 + 2359296);   // [512][64]
    unsigned short* Y3p = (unsigned short*)(w8 + 2424832);   // [512][32] (k>=16 zero)
    float* hcl  = (float*)(w8 + 2457600);                    // [512][3]
    float* rs   = (float*)(w8 + 2463744);                    // [4][512]
    float* adds = (float*)(w8 + 2471936);                    // [512][4]

    hipMemsetAsync(rs, 0, 4 * NTOK * sizeof(float), stream);

    // hidden -> bf16
    conv_bf16<<<512, 256, 0, stream>>>(hidden, Hb, NTOK * 1024 / 4);

    // projections: Y_i = Hb @ proj_i^T   (MODE 0, bf16 out)
    mfma_gemm<0><<<dim3(8, 4), 256, 0, stream>>>(Hb, proj[0], nullptr, nullptr, 0, Y0b, 1024, nullptr, nullptr, 0, 1024, 1024, 1024, 1024);
    mfma_gemm<0><<<dim3(2, 4), 256, 0, stream>>>(Hb, proj[1], nullptr, nullptr, 0, Y1b, 256,  nullptr, nullptr, 0, 256,  1024, 1024, 1024);
    mfma_gemm<0><<<dim3(1, 4), 256, 0, stream>>>(Hb, proj[2], nullptr, nullptr, 0, Y2b, 64,   nullptr, nullptr, 0, 64,   1024, 1024, 1024);
    mfma_gemm<0><<<dim3(1, 4), 256, 0, stream>>>(Hb, proj[3], nullptr, nullptr, 0, Y3p, 32,   nullptr, nullptr, 0, 16,   1024, 1024, 1024);

    // cluster logits from Y0
    hcl_kernel<<<NTOK, 256, 0, stream>>>(Y0b, cw, cb, hcl);

    // stats passes (sum-exp per row, no stores)
    mfma_gemm<1><<<dim3(157, 4),  256, 0, stream>>>(Y0b, W[0], b[0], nullptr, 0, nullptr, 0, rs + 0 * NTOK, nullptr, 0, 20000,  1024, 1024, 1024);
    mfma_gemm<1><<<dim3(157, 4),  256, 0, stream>>>(Y1b, W[1], b[1], nullptr, 0, nullptr, 0, rs + 1 * NTOK, nullptr, 0, 20000,  256,  256,  256);
    mfma_gemm<1><<<dim3(1250, 4), 256, 0, stream>>>(Y2b, W[2], b[2], nullptr, 0, nullptr, 0, rs + 2 * NTOK, nullptr, 0, 160000, 64,   64,   64);
    mfma_gemm<1><<<dim3(530, 4),  256, 0, stream>>>(Y3p, W[3], b[3], nullptr, 0, nullptr, 0, rs + 3 * NTOK, nullptr, 0, 67735,  32,   32,   16);

    finish_kernel<<<2, 256, 0, stream>>>(rs, hcl, adds);

    // write passes (recompute + offset + single fp32 store)
    mfma_gemm<2><<<dim3(157, 4),  256, 0, stream>>>(Y0b, W[0], b[0], out,          VOCAB, nullptr, 0, nullptr, adds, 0, 20000,  1024, 1024, 1024);
    mfma_gemm<2><<<dim3(157, 4),  256, 0, stream>>>(Y1b, W[1], b[1], out + 20000,  VOCAB, nullptr, 0, nullptr, adds, 1, 20000,  256,  256,  256);
    mfma_gemm<2><<<dim3(1250, 4), 256, 0, stream>>>(Y2b, W[2], b[2], out + 40000,  VOCAB, nullptr, 0, nullptr, adds, 2, 160000, 64,   64,   64);
    mfma_gemm<2><<<dim3(530, 4),  256, 0, stream>>>(Y3p, W[3], b[3], out + 200000, VOCAB, nullptr, 0, nullptr, adds, 3, 67735,  32,   32,   16);

    loss_kernel<<<1, NTOK, 0, stream>>>(out, target, out + (size_t)NTOK * VOCAB);
}

// Round 5
// 1161.858 us; speedup vs baseline: 2.9817x; 1.1083x over previous
//
#include <hip/hip_runtime.h>
#include <math.h>

#define VOCAB 267735
#define NTOK  512
#define BM 128
#define BN 128
#define BK 32
#define CDIV(a,b) (((a)+(b)-1)/(b))

typedef __bf16 bf16x8 __attribute__((ext_vector_type(8)));
typedef float f32x4 __attribute__((ext_vector_type(4)));
typedef const __attribute__((address_space(1))) void* gas_ptr;
typedef __attribute__((address_space(3))) void* las_ptr;

__device__ __forceinline__ unsigned short f2bf(float x) {
    unsigned int u = __float_as_uint(x);
    u = (u + 0x7FFFu + ((u >> 16) & 1u)) >> 16;
    return (unsigned short)u;
}
__device__ __forceinline__ float bf2f(unsigned short h) {
    return __uint_as_float(((unsigned int)h) << 16);
}
__device__ __forceinline__ void gload_lds16(const void* g, void* l) {
    __builtin_amdgcn_global_load_lds((gas_ptr)g, (las_ptr)l, 16, 0, 0);
}

// ---------------- fp32 -> bf16 conversion with row/col zero-padding ----------------
// src: [nrows][kb] fp32 ; dst: [npad][ldb] bf16, everything outside [nrows][kb] = 0.
__global__ __launch_bounds__(256) void conv_pad(
    const float* __restrict__ src, unsigned short* __restrict__ dst,
    int nrows, int kb, int npad, int ldb)
{
    size_t idx = (size_t)blockIdx.x * blockDim.x + threadIdx.x;
    size_t tot = (size_t)npad * (size_t)ldb / 8;
    if (idx >= tot) return;
    int ld8 = ldb / 8;
    int r  = (int)(idx / ld8);
    int c8 = (int)(idx % ld8) * 8;
    ushort4 o0 = {0, 0, 0, 0}, o1 = {0, 0, 0, 0};
    if (r < nrows && c8 < kb) {
        const float* s = src + (size_t)r * kb + c8;
        float4 f0 = *(const float4*)s;
        float4 f1 = *(const float4*)(s + 4);
        o0.x = f2bf(f0.x); o0.y = f2bf(f0.y); o0.z = f2bf(f0.z); o0.w = f2bf(f0.w);
        o1.x = f2bf(f1.x); o1.y = f2bf(f1.y); o1.z = f2bf(f1.z); o1.w = f2bf(f1.w);
    }
    ushort4* d = (ushort4*)(dst + (size_t)r * ldb + c8);
    d[0] = o0; d[1] = o1;
}

// ================= NEW PATH: all-bf16 GEMM, both operands via global_load_lds =================
// A: [M][lda] bf16; B: [Npad][ldb] bf16 (row/col pads are zeros). K multiple of 32.
// MODE 0: Yo[gm*ldo+gn] = bf16(acc) for gn<ldo
// MODE 1: rowsum[gm] += sum_n exp(acc + bias[gn])   (gn<N only)
// MODE 2: C[gm*ldc+gn] = acc + bias[gn] + adds[gm*4+seg]  (gn<N only)
template<int MODE>
__global__ __launch_bounds__(256) void mfma_gemm2(
    const unsigned short* __restrict__ Ab, int lda,
    const unsigned short* __restrict__ Bb, int ldb,
    const float* __restrict__ bias,
    float* __restrict__ C, int ldc,
    unsigned short* __restrict__ Yo, int ldo,
    float* __restrict__ rowsum,
    const float* __restrict__ adds, int seg,
    int N, int K)
{
    __shared__ unsigned short As[BM * BK];
    __shared__ unsigned short Bs[BN * BK];
    const int tid  = threadIdx.x;
    const int lane = tid & 63;
    const int w    = tid >> 6;
    const int wm   = w >> 1, wn = w & 1;
    const int mBase = blockIdx.y * BM;
    const int nBase = blockIdx.x * BN;
    const int col = lane & 15, rg = lane >> 4;

    f32x4 acc[4][4] = {};

    for (int k0 = 0; k0 < K; k0 += BK) {
        #pragma unroll
        for (int i = 0; i < 2; ++i) {
            int c = tid + i * 256;              // 0..511
            int m = c >> 2, k8 = (c & 3) * 8;
            gload_lds16(Ab + (size_t)(mBase + m) * lda + k0 + k8, &As[(size_t)c * 8]);
        }
        #pragma unroll
        for (int i = 0; i < 2; ++i) {
            int c = tid + i * 256;
            int n = c >> 2, k8 = (c & 3) * 8;
            gload_lds16(Bb + (size_t)(nBase + n) * ldb + k0 + k8, &Bs[(size_t)c * 8]);
        }
        __syncthreads();
        bf16x8 af[4], bfr[4];
        #pragma unroll
        for (int mi = 0; mi < 4; ++mi) {
            int row = wm * 64 + mi * 16 + col;
            af[mi] = *(const bf16x8*)&As[row * BK + rg * 8];
        }
        #pragma unroll
        for (int ni = 0; ni < 4; ++ni) {
            int row = wn * 64 + ni * 16 + col;
            bfr[ni] = *(const bf16x8*)&Bs[row * BK + rg * 8];
        }
        #pragma unroll
        for (int mi = 0; mi < 4; ++mi)
            #pragma unroll
            for (int ni = 0; ni < 4; ++ni)
                acc[mi][ni] = __builtin_amdgcn_mfma_f32_16x16x32_bf16(
                    af[mi], bfr[ni], acc[mi][ni], 0, 0, 0);
        __syncthreads();
    }

    if (MODE == 1) {
        #pragma unroll
        for (int mi = 0; mi < 4; ++mi) {
            float part[4] = {0.f, 0.f, 0.f, 0.f};
            #pragma unroll
            for (int ni = 0; ni < 4; ++ni) {
                int gn = nBase + wn * 64 + ni * 16 + col;
                if (gn < N) {
                    float bv = bias[gn];
                    #pragma unroll
                    for (int r = 0; r < 4; ++r)
                        part[r] += __expf(acc[mi][ni][r] + bv);
                }
            }
            int gm = mBase + wm * 64 + mi * 16 + rg * 4;
            #pragma unroll
            for (int r = 0; r < 4; ++r) {
                float v = part[r];
                #pragma unroll
                for (int s = 8; s >= 1; s >>= 1) v += __shfl_xor(v, s, 16);
                if (col == 0) atomicAdd(&rowsum[gm + r], v);
            }
        }
    } else if (MODE == 2) {
        #pragma unroll
        for (int mi = 0; mi < 4; ++mi) {
            int gm = mBase + wm * 64 + mi * 16 + rg * 4;
            float av[4];
            #pragma unroll
            for (int r = 0; r < 4; ++r) av[r] = adds[(gm + r) * 4 + seg];
            #pragma unroll
            for (int ni = 0; ni < 4; ++ni) {
                int gn = nBase + wn * 64 + ni * 16 + col;
                if (gn < N) {
                    float bv = bias[gn];
                    #pragma unroll
                    for (int r = 0; r < 4; ++r)
                        C[(size_t)(gm + r) * ldc + gn] = acc[mi][ni][r] + bv + av[r];
                }
            }
        }
    } else {
        #pragma unroll
        for (int mi = 0; mi < 4; ++mi) {
            int gm = mBase + wm * 64 + mi * 16 + rg * 4;
            #pragma unroll
            for (int ni = 0; ni < 4; ++ni) {
                int gn = nBase + wn * 64 + ni * 16 + col;
                if (gn < ldo) {
                    #pragma unroll
                    for (int r = 0; r < 4; ++r)
                        Yo[(size_t)(gm + r) * ldo + gn] = f2bf(acc[mi][ni][r]);
                }
            }
        }
    }
}

// ================= FALLBACK PATH (round-4 kernel, fp32 B reg-staged) =================
template<int MODE>
__global__ __launch_bounds__(256) void mfma_gemm(
    const unsigned short* __restrict__ Ab, const float* __restrict__ Bf,
    const float* __restrict__ bias,
    float* __restrict__ C, int ldc,
    unsigned short* __restrict__ Yo, int ldo,
    float* __restrict__ rowsum,
    const float* __restrict__ adds, int seg,
    int N, int K, int lda, int KB)
{
    __shared__ unsigned short As[BM * BK];
    __shared__ unsigned short Bs[BN * BK];
    const int tid  = threadIdx.x;
    const int lane = tid & 63;
    const int w    = tid >> 6;
    const int wm   = w >> 1, wn = w & 1;
    const int mBase = blockIdx.y * BM;
    const int nBase = blockIdx.x * BN;
    const int col = lane & 15, rg = lane >> 4;

    f32x4 acc[4][4] = {};

    for (int k0 = 0; k0 < K; k0 += BK) {
        #pragma unroll
        for (int i = 0; i < 2; ++i) {
            int c = tid + i * 256;
            int m = c >> 2, k8 = (c & 3) * 8;
            gload_lds16(Ab + (size_t)(mBase + m) * lda + k0 + k8, &As[(size_t)c * 8]);
        }
        #pragma unroll
        for (int i = 0; i < 4; ++i) {
            int c = tid + i * 256;
            int n = c >> 3, k = (c & 7) * 4;
            int gn = nBase + n; if (gn >= N) gn = N - 1;
            int kg = k0 + k;
            float4 f = make_float4(0.f, 0.f, 0.f, 0.f);
            if (kg < KB) f = *(const float4*)(Bf + (size_t)gn * KB + kg);
            ushort4 o;
            o.x = f2bf(f.x); o.y = f2bf(f.y); o.z = f2bf(f.z); o.w = f2bf(f.w);
            *(ushort4*)&Bs[n * BK + k] = o;
        }
        __syncthreads();
        bf16x8 af[4], bfr[4];
        #pragma unroll
        for (int mi = 0; mi < 4; ++mi)
            af[mi] = *(const bf16x8*)&As[(wm * 64 + mi * 16 + col) * BK + rg * 8];
        #pragma unroll
        for (int ni = 0; ni < 4; ++ni)
            bfr[ni] = *(const bf16x8*)&Bs[(wn * 64 + ni * 16 + col) * BK + rg * 8];
        #pragma unroll
        for (int mi = 0; mi < 4; ++mi)
            #pragma unroll
            for (int ni = 0; ni < 4; ++ni)
                acc[mi][ni] = __builtin_amdgcn_mfma_f32_16x16x32_bf16(
                    af[mi], bfr[ni], acc[mi][ni], 0, 0, 0);
        __syncthreads();
    }

    if (MODE == 1) {
        #pragma unroll
        for (int mi = 0; mi < 4; ++mi) {
            float part[4] = {0.f, 0.f, 0.f, 0.f};
            #pragma unroll
            for (int ni = 0; ni < 4; ++ni) {
                int gn = nBase + wn * 64 + ni * 16 + col;
                if (gn < N) {
                    float bv = bias[gn];
                    #pragma unroll
                    for (int r = 0; r < 4; ++r)
                        part[r] += __expf(acc[mi][ni][r] + bv);
                }
            }
            int gm = mBase + wm * 64 + mi * 16 + rg * 4;
            #pragma unroll
            for (int r = 0; r < 4; ++r) {
                float v = part[r];
                #pragma unroll
                for (int s = 8; s >= 1; s >>= 1) v += __shfl_xor(v, s, 16);
                if (col == 0) atomicAdd(&rowsum[gm + r], v);
            }
        }
    } else if (MODE == 2) {
        #pragma unroll
        for (int mi = 0; mi < 4; ++mi) {
            int gm = mBase + wm * 64 + mi * 16 + rg * 4;
            float av[4];
            #pragma unroll
            for (int r = 0; r < 4; ++r) av[r] = adds[(gm + r) * 4 + seg];
            #pragma unroll
            for (int ni = 0; ni < 4; ++ni) {
                int gn = nBase + wn * 64 + ni * 16 + col;
                if (gn < N) {
                    float bv = bias[gn];
                    #pragma unroll
                    for (int r = 0; r < 4; ++r)
                        C[(size_t)(gm + r) * ldc + gn] = acc[mi][ni][r] + bv + av[r];
                }
            }
        }
    } else {
        #pragma unroll
        for (int mi = 0; mi < 4; ++mi) {
            int gm = mBase + wm * 64 + mi * 16 + rg * 4;
            #pragma unroll
            for (int ni = 0; ni < 4; ++ni) {
                int gn = nBase + wn * 64 + ni * 16 + col;
                if (gn < ldo) {
                    #pragma unroll
                    for (int r = 0; r < 4; ++r) {
                        float v = (gn < N) ? acc[mi][ni][r] : 0.f;
                        Yo[(size_t)(gm + r) * ldo + gn] = f2bf(v);
                    }
                }
            }
        }
    }
}

// ---------------- cluster logits ----------------
__global__ __launch_bounds__(256) void hcl_kernel(
    const unsigned short* __restrict__ Y0b, const float* __restrict__ cw,
    const float* __restrict__ cb, float* __restrict__ hcl)
{
    int t = blockIdx.x;
    int w = threadIdx.x >> 6, l = threadIdx.x & 63;
    if (w >= 3) return;
    const unsigned short* yrow = Y0b + (size_t)t * 1024;
    float s = 0.f;
    #pragma unroll
    for (int e = 0; e < 16; ++e) {
        int k = l * 16 + e;
        s += bf2f(yrow[k]) * cw[w * 1024 + k];
    }
    #pragma unroll
    for (int off = 32; off > 0; off >>= 1) s += __shfl_down(s, off, 64);
    if (l == 0) hcl[t * 3 + w] = s + cb[w];
}

// ---------------- finish ----------------
__global__ __launch_bounds__(256) void finish_kernel(
    const float* __restrict__ rs, const float* __restrict__ hcl,
    float* __restrict__ adds)
{
    int t = blockIdx.x * blockDim.x + threadIdx.x;
    if (t >= NTOK) return;
    float h0 = hcl[t * 3 + 0], h1 = hcl[t * 3 + 1], h2 = hcl[t * 3 + 2];
    float s_head = rs[0 * NTOK + t] + __expf(h0) + __expf(h1) + __expf(h2);
    float lse_head = __logf(s_head);
    adds[t * 4 + 0] = -lse_head;
    adds[t * 4 + 1] = (h0 - lse_head) - __logf(rs[1 * NTOK + t]);
    adds[t * 4 + 2] = (h1 - lse_head) - __logf(rs[2 * NTOK + t]);
    adds[t * 4 + 3] = (h2 - lse_head) - __logf(rs[3 * NTOK + t]);
}

// ---------------- loss ----------------
__global__ __launch_bounds__(512) void loss_kernel(
    const float* __restrict__ out, const int* __restrict__ target,
    float* __restrict__ loss)
{
    __shared__ float sm[8];
    const int t = threadIdx.x;
    float v = -out[(size_t)t * VOCAB + target[t]];
    #pragma unroll
    for (int off = 32; off > 0; off >>= 1) v += __shfl_down(v, off, 64);
    int wid = threadIdx.x >> 6, lane = threadIdx.x & 63;
    if (lane == 0) sm[wid] = v;
    __syncthreads();
    if (threadIdx.x == 0) {
        float s = 0.f;
        for (int i = 0; i < 8; ++i) s += sm[i];
        *loss = s / (float)NTOK;
    }
}

// ---------------- launch ----------------
extern "C" void kernel_launch(void* const* d_in, const int* in_sizes, int n_in,
                              void* d_out, int out_size, void* d_ws, size_t ws_size,
                              hipStream_t stream)
{
    const float* hidden = (const float*)d_in[0];
    const int*   target = (const int*)d_in[1];
    const float* cw     = (const float*)d_in[2];
    const float* cb     = (const float*)d_in[3];
    const float* proj[4] = {(const float*)d_in[4], (const float*)d_in[7],
                            (const float*)d_in[10], (const float*)d_in[13]};
    const float* W[4]    = {(const float*)d_in[5], (const float*)d_in[8],
                            (const float*)d_in[11], (const float*)d_in[14]};
    const float* b[4]    = {(const float*)d_in[6], (const float*)d_in[9],
                            (const float*)d_in[12], (const float*)d_in[15]};
    float* out = (float*)d_out;
    char*  w8  = (char*)d_ws;
    dim3 blk(256);

    // ---- workspace layout ----
    size_t off = 0;
    auto alloc = [&](size_t bytes) { size_t o = off; off += (bytes + 255) & ~(size_t)255; return o; };
    size_t oHb  = alloc(512 * 1024 * 2);
    size_t oY0  = alloc(512 * 1024 * 2);
    size_t oY1  = alloc(512 * 256 * 2);
    size_t oY2  = alloc(512 * 64 * 2);
    size_t oY3  = alloc(512 * 32 * 2);
    size_t ohcl = alloc(512 * 3 * 4);
    size_t ors  = alloc(4 * 512 * 4);
    size_t oadd = alloc(512 * 4 * 4);
    size_t small_end = off;
    // bf16 arenas (new path only)
    size_t oP0  = alloc((size_t)1024 * 1024 * 2);
    size_t oP1  = alloc((size_t)256 * 1024 * 2);
    size_t oP2  = alloc((size_t)128 * 1024 * 2);
    size_t oP3  = alloc((size_t)128 * 1024 * 2);
    size_t oW0  = alloc((size_t)20096 * 1024 * 2);
    size_t oW1  = alloc((size_t)20096 * 256 * 2);
    size_t oW2  = alloc((size_t)160000 * 64 * 2);
    size_t oW3  = alloc((size_t)67840 * 32 * 2);
    size_t need = off;

    unsigned short* Hb  = (unsigned short*)(w8 + oHb);
    unsigned short* Y0b = (unsigned short*)(w8 + oY0);
    unsigned short* Y1b = (unsigned short*)(w8 + oY1);
    unsigned short* Y2b = (unsigned short*)(w8 + oY2);
    unsigned short* Y3p = (unsigned short*)(w8 + oY3);
    float* hcl  = (float*)(w8 + ohcl);
    float* rs   = (float*)(w8 + ors);
    float* adds = (float*)(w8 + oadd);

    hipMemsetAsync(rs, 0, 4 * NTOK * sizeof(float), stream);

    // hidden -> bf16 (both paths)
    conv_pad<<<CDIV(512 * 1024 / 8, 256), blk, 0, stream>>>(hidden, Hb, 512, 1024, 512, 1024);

    if (ws_size >= need) {
        // ======== NEW PATH: all-bf16 arenas + dual global_load_lds GEMM ========
        unsigned short* P0a = (unsigned short*)(w8 + oP0);
        unsigned short* P1a = (unsigned short*)(w8 + oP1);
        unsigned short* P2a = (unsigned short*)(w8 + oP2);
        unsigned short* P3a = (unsigned short*)(w8 + oP3);
        unsigned short* W0a = (unsigned short*)(w8 + oW0);
        unsigned short* W1a = (unsigned short*)(w8 + oW1);
        unsigned short* W2a = (unsigned short*)(w8 + oW2);
        unsigned short* W3a = (unsigned short*)(w8 + oW3);

        conv_pad<<<CDIV(1024 * 1024 / 8, 256), blk, 0, stream>>>(proj[0], P0a, 1024, 1024, 1024, 1024);
        conv_pad<<<CDIV(256 * 1024 / 8, 256), blk, 0, stream>>>(proj[1], P1a, 256, 1024, 256, 1024);
        conv_pad<<<CDIV(128 * 1024 / 8, 256), blk, 0, stream>>>(proj[2], P2a, 64, 1024, 128, 1024);
        conv_pad<<<CDIV(128 * 1024 / 8, 256), blk, 0, stream>>>(proj[3], P3a, 16, 1024, 128, 1024);
        conv_pad<<<CDIV(20096 * 1024 / 8, 256), blk, 0, stream>>>(W[0], W0a, 20000, 1024, 20096, 1024);
        conv_pad<<<CDIV(20096 * 256 / 8, 256), blk, 0, stream>>>(W[1], W1a, 20000, 256, 20096, 256);
        conv_pad<<<CDIV(160000 * 64 / 8, 256), blk, 0, stream>>>(W[2], W2a, 160000, 64, 160000, 64);
        conv_pad<<<CDIV(67840 * 32 / 8, 256), blk, 0, stream>>>(W[3], W3a, 67735, 16, 67840, 32);

        // projections (MODE 0)
        mfma_gemm2<0><<<dim3(8, 4), blk, 0, stream>>>(Hb, 1024, P0a, 1024, nullptr, nullptr, 0, Y0b, 1024, nullptr, nullptr, 0, 1024, 1024);
        mfma_gemm2<0><<<dim3(2, 4), blk, 0, stream>>>(Hb, 1024, P1a, 1024, nullptr, nullptr, 0, Y1b, 256, nullptr, nullptr, 0, 256, 1024);
        mfma_gemm2<0><<<dim3(1, 4), blk, 0, stream>>>(Hb, 1024, P2a, 1024, nullptr, nullptr, 0, Y2b, 64, nullptr, nullptr, 0, 64, 1024);
        mfma_gemm2<0><<<dim3(1, 4), blk, 0, stream>>>(Hb, 1024, P3a, 1024, nullptr, nullptr, 0, Y3p, 32, nullptr, nullptr, 0, 16, 1024);

        hcl_kernel<<<NTOK, blk, 0, stream>>>(Y0b, cw, cb, hcl);

        // stats passes
        mfma_gemm2<1><<<dim3(157, 4), blk, 0, stream>>>(Y0b, 1024, W0a, 1024, b[0], nullptr, 0, nullptr, 0, rs + 0 * NTOK, nullptr, 0, 20000, 1024);
        mfma_gemm2<1><<<dim3(157, 4), blk, 0, stream>>>(Y1b, 256, W1a, 256, b[1], nullptr, 0, nullptr, 0, rs + 1 * NTOK, nullptr, 0, 20000, 256);
        mfma_gemm2<1><<<dim3(1250, 4), blk, 0, stream>>>(Y2b, 64, W2a, 64, b[2], nullptr, 0, nullptr, 0, rs + 2 * NTOK, nullptr, 0, 160000, 64);
        mfma_gemm2<1><<<dim3(530, 4), blk, 0, stream>>>(Y3p, 32, W3a, 32, b[3], nullptr, 0, nullptr, 0, rs + 3 * NTOK, nullptr, 0, 67735, 32);

        finish_kernel<<<2, blk, 0, stream>>>(rs, hcl, adds);

        // write passes
        mfma_gemm2<2><<<dim3(157, 4), blk, 0, stream>>>(Y0b, 1024, W0a, 1024, b[0], out, VOCAB, nullptr, 0, nullptr, adds, 0, 20000, 1024);
        mfma_gemm2<2><<<dim3(157, 4), blk, 0, stream>>>(Y1b, 256, W1a, 256, b[1], out + 20000, VOCAB, nullptr, 0, nullptr, adds, 1, 20000, 256);
        mfma_gemm2<2><<<dim3(1250, 4), blk, 0, stream>>>(Y2b, 64, W2a, 64, b[2], out + 40000, VOCAB, nullptr, 0, nullptr, adds, 2, 160000, 64);
        mfma_gemm2<2><<<dim3(530, 4), blk, 0, stream>>>(Y3p, 32, W3a, 32, b[3], out + 200000, VOCAB, nullptr, 0, nullptr, adds, 3, 67735, 32);
    } else {
        // ======== FALLBACK (round-4): fp32 B reg-staged ========
        (void)small_end;
        mfma_gemm<0><<<dim3(8, 4), blk, 0, stream>>>(Hb, proj[0], nullptr, nullptr, 0, Y0b, 1024, nullptr, nullptr, 0, 1024, 1024, 1024, 1024);
        mfma_gemm<0><<<dim3(2, 4), blk, 0, stream>>>(Hb, proj[1], nullptr, nullptr, 0, Y1b, 256, nullptr, nullptr, 0, 256, 1024, 1024, 1024);
        mfma_gemm<0><<<dim3(1, 4), blk, 0, stream>>>(Hb, proj[2], nullptr, nullptr, 0, Y2b, 64, nullptr, nullptr, 0, 64, 1024, 1024, 1024);
        mfma_gemm<0><<<dim3(1, 4), blk, 0, stream>>>(Hb, proj[3], nullptr, nullptr, 0, Y3p, 32, nullptr, nullptr, 0, 16, 1024, 1024, 1024);

        hcl_kernel<<<NTOK, blk, 0, stream>>>(Y0b, cw, cb, hcl);

        mfma_gemm<1><<<dim3(157, 4), blk, 0, stream>>>(Y0b, W[0], b[0], nullptr, 0, nullptr, 0, rs + 0 * NTOK, nullptr, 0, 20000, 1024, 1024, 1024);
        mfma_gemm<1><<<dim3(157, 4), blk, 0, stream>>>(Y1b, W[1], b[1], nullptr, 0, nullptr, 0, rs + 1 * NTOK, nullptr, 0, 20000, 256, 256, 256);
        mfma_gemm<1><<<dim3(1250, 4), blk, 0, stream>>>(Y2b, W[2], b[2], nullptr, 0, nullptr, 0, rs + 2 * NTOK, nullptr, 0, 160000, 64, 64, 64);
        mfma_gemm<1><<<dim3(530, 4), blk, 0, stream>>>(Y3p, W[3], b[3], nullptr, 0, nullptr, 0, rs + 3 * NTOK, nullptr, 0, 67735, 32, 32, 16);

        finish_kernel<<<2, blk, 0, stream>>>(rs, hcl, adds);

        mfma_gemm<2><<<dim3(157, 4), blk, 0, stream>>>(Y0b, W[0], b[0], out, VOCAB, nullptr, 0, nullptr, adds, 0, 20000, 1024, 1024, 1024);
        mfma_gemm<2><<<dim3(157, 4), blk, 0, stream>>>(Y1b, W[1], b[1], out + 20000, VOCAB, nullptr, 0, nullptr, adds, 1, 20000, 256, 256, 256);
        mfma_gemm<2><<<dim3(1250, 4), blk, 0, stream>>>(Y2b, W[2], b[2], out + 40000, VOCAB, nullptr, 0, nullptr, adds, 2, 160000, 64, 64, 64);
        mfma_gemm<2><<<dim3(530, 4), blk, 0, stream>>>(Y3p, W[3], b[3], out + 200000, VOCAB, nullptr, 0, nullptr, adds, 3, 67735, 32, 32, 16);
    }

    loss_kernel<<<1, NTOK, 0, stream>>>(out, target, out + (size_t)NTOK * VOCAB);
}